// Round 6
// baseline (165.856 us; speedup 1.0000x reference)
//
#include <hip/hip_runtime.h>

typedef unsigned short ushortT;
typedef unsigned int uintT;
typedef __attribute__((ext_vector_type(8))) short bf16x8;
typedef __attribute__((ext_vector_type(4))) float f32x4;

#define B_ 4
#define T_ 1000
#define H_ 16
#define MP 4096
#define QSCALE 0.18033688011112042f   // 0.125 * log2(e)

__device__ __forceinline__ ushortT f2bf(float f) {
    unsigned u = __float_as_uint(f);
    u += 0x7fffu + ((u >> 16) & 1u);   // round-to-nearest-even
    return (ushortT)(u >> 16);
}
__device__ __forceinline__ float fast_exp2(float x) {
#if __has_builtin(__builtin_amdgcn_exp2f)
    return __builtin_amdgcn_exp2f(x);
#else
    return exp2f(x);
#endif
}

// ================ prep: cast x -> Xb (padded rows b*1024+t) + transpose both W
__global__ void prep_kernel(const float* __restrict__ x,
                            const float* __restrict__ Wa, const float* __restrict__ Wp,
                            ushortT* __restrict__ Xb,
                            ushortT* __restrict__ Wat, ushortT* __restrict__ Wpt) {
    __shared__ float tile[64][65];
    int bid = blockIdx.x, tid = threadIdx.x;
    if (bid < 4096) {
        int e = (bid * 256 + tid) * 4;
        int r = e >> 10, col = e & 1023;
        int b = r >> 10, t = r & 1023;
        ushort4 o = make_ushort4(0, 0, 0, 0);
        if (t < T_) {
            float4 v = *(const float4*)(x + (((size_t)(b * T_ + t)) << 10) + col);
            o.x = f2bf(v.x); o.y = f2bf(v.y); o.z = f2bf(v.z); o.w = f2bf(v.w);
        }
        *(ushort4*)(Xb + (size_t)e) = o;
        return;
    }
    const float* W; ushortT* Wt; int N, bx, by;
    if (bid < 4096 + 768) { W = Wa; Wt = Wat; N = 3072; int id = bid - 4096; bx = id % 48; by = id / 48; }
    else                  { W = Wp; Wt = Wpt; N = 1024; int id = bid - 4864; bx = id & 15; by = id >> 4; }
    int k0 = by * 64, n0 = bx * 64;
    int lane = tid & 63, w4 = tid >> 6;
#pragma unroll 4
    for (int i = 0; i < 16; ++i) {
        int row = i * 4 + w4;
        tile[row][lane] = W[(size_t)(k0 + row) * N + n0 + lane];
    }
    __syncthreads();
#pragma unroll 4
    for (int i = 0; i < 16; ++i) {
        int row = i * 4 + w4;
        Wt[(size_t)(n0 + row) * 1024 + k0 + lane] = f2bf(tile[lane][row]);
    }
}

// ================ QKV GEMM with fused RoPE/pack/V-transpose epilogue (3 blocks/CU)
__global__ __launch_bounds__(256, 3) void gemm_qkv_kernel(
    const ushortT* __restrict__ A, const ushortT* __restrict__ Bt,
    ushortT* __restrict__ Qb, ushortT* __restrict__ Kb, ushortT* __restrict__ Vtb)
{
    __shared__ __align__(16) ushortT smem[16896];
    ushortT* As = smem;
    ushortT* Bs = smem + 8192;
    const int K = 1024;
    int tid = threadIdx.x, wave = tid >> 6, lane = tid & 63;
    int m0 = blockIdx.y * 128, n0 = blockIdx.x * 128;
    int wm = (wave >> 1) * 64, wn = (wave & 1) * 64;
    int col0 = lane & 15, quad = lane >> 4;

    f32x4 acc[4][4] = {};

    for (int kt = 0; kt < 16; ++kt) {
        int k0 = kt * 64;
        __syncthreads();
#pragma unroll
        for (int it = 0; it < 4; ++it) {
            int gci = (wave * 4 + it) * 64 + lane;
            int r = gci >> 3, c = gci & 7;
            int sc = c ^ (r & 7);
            const ushortT* ga = A + (size_t)(m0 + r) * K + k0 + sc * 8;
            __builtin_amdgcn_global_load_lds(
                (const __attribute__((address_space(1))) unsigned int*)ga,
                (__attribute__((address_space(3))) unsigned int*)(As + (wave * 4 + it) * 512),
                16, 0, 0);
            const ushortT* gb = Bt + (size_t)(n0 + r) * K + k0 + sc * 8;
            __builtin_amdgcn_global_load_lds(
                (const __attribute__((address_space(1))) unsigned int*)gb,
                (__attribute__((address_space(3))) unsigned int*)(Bs + (wave * 4 + it) * 512),
                16, 0, 0);
        }
        __syncthreads();
#pragma unroll
        for (int s = 0; s < 2; ++s) {
            int g = s * 4 + quad;
            bf16x8 af[4], bfr[4];
#pragma unroll
            for (int mi = 0; mi < 4; ++mi) {
                int r = wm + mi * 16 + col0;
                af[mi] = *(const bf16x8*)(As + r * 64 + ((g ^ (r & 7)) * 8));
            }
#pragma unroll
            for (int ni = 0; ni < 4; ++ni) {
                int r = wn + ni * 16 + col0;
                bfr[ni] = *(const bf16x8*)(Bs + r * 64 + ((g ^ (r & 7)) * 8));
            }
#pragma unroll
            for (int mi = 0; mi < 4; ++mi)
#pragma unroll
                for (int ni = 0; ni < 4; ++ni)
                    acc[mi][ni] = __builtin_amdgcn_mfma_f32_16x16x32_bf16(
                        af[mi], bfr[ni], acc[mi][ni], 0, 0, 0);
        }
    }
    __syncthreads();

    int sec = n0 >> 10, cb = n0 & 1023;
    int b = m0 >> 10, tbase = m0 & 1023;

    if (sec < 2) {
        float2* tab = (float2*)smem;   // [tl][p], stride 33
#pragma unroll
        for (int i = 0; i < 16; ++i) {
            int task = i * 256 + tid;
            int tl = task >> 5, p = task & 31;
            float theta = __expf(-(float)p * 0.28782313662425572f);
            float ang = (float)(tbase + tl) * theta;
            float sn, cs;
            sincosf(ang, &sn, &cs);
            tab[tl * 33 + p] = make_float2(cs, sn);
        }
        __syncthreads();
        ushortT* Out = sec ? Kb : Qb;
        float qs = sec ? 1.0f : QSCALE;
#pragma unroll
        for (int mi = 0; mi < 4; ++mi) {
#pragma unroll
            for (int j = 0; j < 4; ++j) {
                int tl = wm + mi * 16 + quad * 4 + j;
                int t = tbase + tl;
                bool valid = t < T_;
#pragma unroll
                for (int nt = 0; nt < 4; ++nt) {
                    float xv = acc[mi][nt][j];
                    float xp = __shfl_xor(xv, 1);
                    int cl = wn + nt * 16 + col0;
                    int d = cl & 63;
                    float2 cssn = tab[tl * 33 + (d >> 1)];
                    float r = (d & 1) ? (xv * cssn.x + xp * cssn.y)
                                      : (xv * cssn.x - xp * cssn.y);
                    r *= qs;
                    if (valid)
                        Out[((size_t)((b << 4) | ((cb + cl) >> 6)) << 16) + (t << 6) + d] = f2bf(r);
                }
            }
        }
    } else {
        ushortT* Ls = smem;   // [col 128][stride 132]
#pragma unroll
        for (int mi = 0; mi < 4; ++mi) {
#pragma unroll
            for (int nt = 0; nt < 4; ++nt) {
                int cl = wn + nt * 16 + col0;
                int rb = wm + mi * 16 + quad * 4;
                uintT lo = (uintT)f2bf(acc[mi][nt][0]) | ((uintT)f2bf(acc[mi][nt][1]) << 16);
                uintT hi = (uintT)f2bf(acc[mi][nt][2]) | ((uintT)f2bf(acc[mi][nt][3]) << 16);
                *(uint2*)(Ls + cl * 132 + rb) = make_uint2(lo, hi);
            }
        }
        __syncthreads();
#pragma unroll
        for (int it = 0; it < 8; ++it) {
            int u = it * 256 + tid;
            int cl = u >> 4, c = u & 15;
            int d = cl & 63, h = (cb + cl) >> 6;
            ushortT tmp[8];
#pragma unroll
            for (int j = 0; j < 8; ++j) tmp[j] = Ls[cl * 132 + j * 16 + c];
            *(bf16x8*)(Vtb + (((size_t)((b << 4) | h)) << 16) + ((size_t)d << 10) + tbase + c * 8)
                = *(bf16x8*)tmp;
        }
    }
}

// ================ MFMA flash attention — paired complementary q-tiles
// Block (bh, p) handles q-tiles qa=p and qb=15-p (64 rows each): total work = 9
// chunk-units for EVERY block (perfect balance). Tile A's K/V chunks are a prefix
// of tile B's -> shared staging. Ps reused sequentially per wave (wave-local).
#define PSTR 136
template <bool LAST>
__device__ __forceinline__ void softmax_store(f32x4* sc4, ushortT* Ps,
                                              int wave, int quad, int col0,
                                              int qrow0, int j0) {
#pragma unroll
    for (int reg = 0; reg < 4; ++reg) {
        int m = quad * 4 + reg;
        int q = qrow0 + m;
        float pv[8];
#pragma unroll
        for (int nt = 0; nt < 8; ++nt) {
            float p = fast_exp2(sc4[nt][reg]);
            if (LAST && (j0 + nt * 16 + col0) > q) p = 0.f;
            pv[nt] = p;
        }
        int4 pk;
        pk.x = __builtin_amdgcn_perm(__float_as_uint(pv[1]), __float_as_uint(pv[0]), 0x07060302u);
        pk.y = __builtin_amdgcn_perm(__float_as_uint(pv[3]), __float_as_uint(pv[2]), 0x07060302u);
        pk.z = __builtin_amdgcn_perm(__float_as_uint(pv[5]), __float_as_uint(pv[4]), 0x07060302u);
        pk.w = __builtin_amdgcn_perm(__float_as_uint(pv[7]), __float_as_uint(pv[6]), 0x07060302u);
        *(int4*)(Ps + (wave * 16 + m) * PSTR + col0 * 8) = pk;
    }
}

__global__ __launch_bounds__(256, 3) void attn_mfma_kernel(
    const ushortT* __restrict__ Qb, const ushortT* __restrict__ Kb,
    const ushortT* __restrict__ Vtb, ushortT* __restrict__ Yb)
{
    __shared__ __align__(16) ushortT Ks[128 * 64];    // 16 KB
    __shared__ __align__(16) ushortT Vs[64 * 128];    // 16 KB
    __shared__ __align__(16) ushortT Ps[64 * PSTR];   // 17 KB  (per-wave slice, reused by both tiles)

    int bh = blockIdx.x;
    int b = bh >> 4, h = bh & 15;
    int p = blockIdx.y;             // pair index 0..7
    int q0u[2];
    q0u[0] = p * 64;                // tile A (light)
    q0u[1] = (15 - p) * 64;         // tile B (heavy)
    int nca = p / 2 + 1;            // A's chunk count
    int ncb = (15 - p) / 2 + 1;     // B's chunk count (>= nca)

    int tid = threadIdx.x, wave = tid >> 6, lane = tid & 63;
    int col0 = lane & 15, quad = lane >> 4;

    const ushortT* Kbh  = Kb  + ((size_t)bh << 16);
    const ushortT* Vtbh = Vtb + ((size_t)bh << 16);

    bf16x8 aq[2][2];
#pragma unroll
    for (int u = 0; u < 2; ++u) {
        const ushortT* qrowp = Qb + ((size_t)bh << 16)
                             + (size_t)(q0u[u] + wave * 16 + col0) * 64;
        aq[u][0] = *(const bf16x8*)(qrowp + quad * 8);
        aq[u][1] = *(const bf16x8*)(qrowp + 32 + quad * 8);
    }

    bf16x8 onesb;
#pragma unroll
    for (int i = 0; i < 8; ++i) onesb[i] = (short)0x3F80;

    f32x4 o[2][4] = {};
    f32x4 lsum[2] = {};

    for (int cc = 0; cc < ncb; ++cc) {
        int j0 = cc * 128;
        __syncthreads();
#pragma unroll
        for (int it = 0; it < 4; ++it) {
            int gci = (wave * 4 + it) * 64 + lane;
            {
                int r = gci >> 3, c = gci & 7;
                int sc = c ^ (r & 7);
                const ushortT* gk = Kbh + (size_t)(j0 + r) * 64 + sc * 8;
                __builtin_amdgcn_global_load_lds(
                    (const __attribute__((address_space(1))) unsigned int*)gk,
                    (__attribute__((address_space(3))) unsigned int*)(Ks + (wave * 4 + it) * 512),
                    16, 0, 0);
            }
            {
                int d = gci >> 4, c = gci & 15;
                int sc = c ^ (d & 15);
                const ushortT* gv = Vtbh + (size_t)d * 1024 + j0 + sc * 8;
                __builtin_amdgcn_global_load_lds(
                    (const __attribute__((address_space(1))) unsigned int*)gv,
                    (__attribute__((address_space(3))) unsigned int*)(Vs + (wave * 4 + it) * 512),
                    16, 0, 0);
            }
        }
        __syncthreads();

#pragma unroll
        for (int u = 0; u < 2; ++u) {
            int ncu = u ? ncb : nca;
            if (cc >= ncu) continue;            // tile done (wave-uniform branch)
            f32x4 sc4[8] = {};
#pragma unroll
            for (int s = 0; s < 2; ++s) {
#pragma unroll
                for (int nt = 0; nt < 8; ++nt) {
                    int r = nt * 16 + col0;
                    bf16x8 bk = *(const bf16x8*)(Ks + r * 64 + (((s * 4 + quad) ^ (col0 & 7)) * 8));
                    sc4[nt] = __builtin_amdgcn_mfma_f32_16x16x32_bf16(aq[u][s], bk, sc4[nt], 0, 0, 0);
                }
            }
            int qrow0 = q0u[u] + wave * 16;
            if (cc == ncu - 1)
                softmax_store<true>(sc4, Ps, wave, quad, col0, qrow0, j0);
            else
                softmax_store<false>(sc4, Ps, wave, quad, col0, qrow0, j0);

#pragma unroll
            for (int s = 0; s < 4; ++s) {
                bf16x8 ap = *(const bf16x8*)(Ps + (wave * 16 + col0) * PSTR + s * 32 + quad * 8);
                lsum[u] = __builtin_amdgcn_mfma_f32_16x16x32_bf16(ap, onesb, lsum[u], 0, 0, 0);
#pragma unroll
                for (int nt = 0; nt < 4; ++nt) {
                    int d = nt * 16 + col0;
                    bf16x8 bv = *(const bf16x8*)(Vs + d * 128 + (((s * 4 + quad) ^ col0) * 8));
                    o[u][nt] = __builtin_amdgcn_mfma_f32_16x16x32_bf16(ap, bv, o[u][nt], 0, 0, 0);
                }
            }
        }
    }

#pragma unroll
    for (int u = 0; u < 2; ++u) {
#pragma unroll
        for (int reg = 0; reg < 4; ++reg) {
            int q = q0u[u] + wave * 16 + quad * 4 + reg;
            if (q < T_) {
                float inv_l = 1.0f / lsum[u][reg];
                ushortT* yp = Yb + ((size_t)(b * 1024 + q) << 10) + h * 64;
#pragma unroll
                for (int nt = 0; nt < 4; ++nt)
                    yp[nt * 16 + col0] = f2bf(o[u][nt][reg] * inv_l);
            }
        }
    }
}

// ================ Proj GEMM: 64x128 tile, row-remap fp32 store
__global__ __launch_bounds__(256, 3) void gemm_proj_kernel(
    const ushortT* __restrict__ A, const ushortT* __restrict__ Bt,
    float* __restrict__ Cout)
{
    __shared__ __align__(16) ushortT As[64 * 64];
    __shared__ __align__(16) ushortT Bs[128 * 64];
    const int K = 1024;
    int tid = threadIdx.x, wave = tid >> 6, lane = tid & 63;
    int m0 = blockIdx.y * 64, n0 = blockIdx.x * 128;
    int wm = (wave >> 1) * 32, wn = (wave & 1) * 64;
    int col0 = lane & 15, quad = lane >> 4;

    f32x4 acc[2][4] = {};

    for (int kt = 0; kt < 16; ++kt) {
        int k0 = kt * 64;
        __syncthreads();
#pragma unroll
        for (int it = 0; it < 2; ++it) {
            int gci = it * 256 + tid;
            int r = gci >> 3, c = gci & 7;
            int sc = c ^ (r & 7);
            const ushortT* ga = A + (size_t)(m0 + r) * K + k0 + sc * 8;
            __builtin_amdgcn_global_load_lds(
                (const __attribute__((address_space(1))) unsigned int*)ga,
                (__attribute__((address_space(3))) unsigned int*)(As + it * 2048 + wave * 512),
                16, 0, 0);
        }
#pragma unroll
        for (int it = 0; it < 4; ++it) {
            int gci = it * 256 + tid;
            int r = gci >> 3, c = gci & 7;
            int sc = c ^ (r & 7);
            const ushortT* gb = Bt + (size_t)(n0 + r) * K + k0 + sc * 8;
            __builtin_amdgcn_global_load_lds(
                (const __attribute__((address_space(1))) unsigned int*)gb,
                (__attribute__((address_space(3))) unsigned int*)(Bs + it * 2048 + wave * 512),
                16, 0, 0);
        }
        __syncthreads();
#pragma unroll
        for (int s = 0; s < 2; ++s) {
            int g = s * 4 + quad;
            bf16x8 af[2], bfr[4];
#pragma unroll
            for (int mi = 0; mi < 2; ++mi) {
                int r = wm + mi * 16 + col0;
                af[mi] = *(const bf16x8*)(As + r * 64 + ((g ^ (r & 7)) * 8));
            }
#pragma unroll
            for (int ni = 0; ni < 4; ++ni) {
                int r = wn + ni * 16 + col0;
                bfr[ni] = *(const bf16x8*)(Bs + r * 64 + ((g ^ (r & 7)) * 8));
            }
#pragma unroll
            for (int mi = 0; mi < 2; ++mi)
#pragma unroll
                for (int ni = 0; ni < 4; ++ni)
                    acc[mi][ni] = __builtin_amdgcn_mfma_f32_16x16x32_bf16(
                        af[mi], bfr[ni], acc[mi][ni], 0, 0, 0);
        }
    }

#pragma unroll
    for (int mi = 0; mi < 2; ++mi) {
#pragma unroll
        for (int j = 0; j < 4; ++j) {
            int row = m0 + wm + mi * 16 + quad * 4 + j;
            int t = row & 1023, b = row >> 10;
            if (t < T_) {
                float* cp = Cout + ((size_t)(b * T_ + t) << 10) + n0 + wn;
#pragma unroll
                for (int ni = 0; ni < 4; ++ni)
                    cp[ni * 16 + col0] = acc[mi][ni][j];
            }
        }
    }
}

extern "C" void kernel_launch(void* const* d_in, const int* in_sizes, int n_in,
                              void* d_out, int out_size, void* d_ws, size_t ws_size,
                              hipStream_t stream) {
    const float* x      = (const float*)d_in[0];
    const float* W_attn = (const float*)d_in[2];
    const float* W_proj = (const float*)d_in[3];
    float* out = (float*)d_out;

    uintptr_t w = (uintptr_t)d_ws;
    ushortT* Xb  = (ushortT*)(w);                   //  8 MB  bf16 [4096][1024] (padded rows)
    ushortT* Wat = (ushortT*)(w + 8388608);         //  6 MB  bf16 [3072][1024]
    ushortT* Wpt = (ushortT*)(w + 14680064);        //  2 MB  bf16 [1024][1024]
    ushortT* Qb  = (ushortT*)(w + 16777216);        //  8 MB  bf16 [64bh][1024][64]
    ushortT* Kb  = (ushortT*)(w + 25165824);        //  8 MB
    ushortT* Vtb = (ushortT*)(w + 33554432);        //  8 MB  bf16 [64bh][64][1024] (pi-permuted)
    ushortT* Yb  = (ushortT*)(w + 41943040);        //  8 MB  bf16 [4096][1024] (padded rows)

    prep_kernel<<<dim3(5120), dim3(256), 0, stream>>>(x, W_attn, W_proj, Xb, Wat, Wpt);

    gemm_qkv_kernel<<<dim3(24, 32), dim3(256), 0, stream>>>(Xb, Wat, Qb, Kb, Vtb);

    attn_mfma_kernel<<<dim3(64, 8), dim3(256), 0, stream>>>(Qb, Kb, Vtb, Yb);

    gemm_proj_kernel<<<dim3(8, 64), dim3(256), 0, stream>>>(Yb, Wpt, out);
}

// Round 7
// 151.362 us; speedup vs baseline: 1.0958x; 1.0958x over previous
//
#include <hip/hip_runtime.h>

typedef unsigned short ushortT;
typedef unsigned int uintT;
typedef __attribute__((ext_vector_type(8))) short bf16x8;
typedef __attribute__((ext_vector_type(4))) float f32x4;

#define B_ 4
#define T_ 1000
#define H_ 16
#define MP 4096
#define QSCALE 0.18033688011112042f   // 0.125 * log2(e)

__device__ __forceinline__ ushortT f2bf(float f) {
    unsigned u = __float_as_uint(f);
    u += 0x7fffu + ((u >> 16) & 1u);   // round-to-nearest-even
    return (ushortT)(u >> 16);
}
__device__ __forceinline__ float fast_exp2(float x) {
#if __has_builtin(__builtin_amdgcn_exp2f)
    return __builtin_amdgcn_exp2f(x);
#else
    return exp2f(x);
#endif
}

// ================ prep: cast x -> Xb (padded rows b*1024+t) + transpose both W
__global__ void prep_kernel(const float* __restrict__ x,
                            const float* __restrict__ Wa, const float* __restrict__ Wp,
                            ushortT* __restrict__ Xb,
                            ushortT* __restrict__ Wat, ushortT* __restrict__ Wpt) {
    __shared__ float tile[64][65];
    int bid = blockIdx.x, tid = threadIdx.x;
    if (bid < 4096) {
        int e = (bid * 256 + tid) * 4;
        int r = e >> 10, col = e & 1023;
        int b = r >> 10, t = r & 1023;
        ushort4 o = make_ushort4(0, 0, 0, 0);
        if (t < T_) {
            float4 v = *(const float4*)(x + (((size_t)(b * T_ + t)) << 10) + col);
            o.x = f2bf(v.x); o.y = f2bf(v.y); o.z = f2bf(v.z); o.w = f2bf(v.w);
        }
        *(ushort4*)(Xb + (size_t)e) = o;
        return;
    }
    const float* W; ushortT* Wt; int N, bx, by;
    if (bid < 4096 + 768) { W = Wa; Wt = Wat; N = 3072; int id = bid - 4096; bx = id % 48; by = id / 48; }
    else                  { W = Wp; Wt = Wpt; N = 1024; int id = bid - 4864; bx = id & 15; by = id >> 4; }
    int k0 = by * 64, n0 = bx * 64;
    int lane = tid & 63, w4 = tid >> 6;
#pragma unroll 4
    for (int i = 0; i < 16; ++i) {
        int row = i * 4 + w4;
        tile[row][lane] = W[(size_t)(k0 + row) * N + n0 + lane];
    }
    __syncthreads();
#pragma unroll 4
    for (int i = 0; i < 16; ++i) {
        int row = i * 4 + w4;
        Wt[(size_t)(n0 + row) * 1024 + k0 + lane] = f2bf(tile[lane][row]);
    }
}

// ================ QKV GEMM with fused RoPE/pack/V-transpose epilogue
__global__ __launch_bounds__(256, 2) void gemm_qkv_kernel(
    const ushortT* __restrict__ A, const ushortT* __restrict__ Bt,
    ushortT* __restrict__ Qb, ushortT* __restrict__ Kb, ushortT* __restrict__ Vtb)
{
    __shared__ __align__(16) ushortT smem[16896];
    ushortT* As = smem;
    ushortT* Bs = smem + 8192;
    const int K = 1024;
    int tid = threadIdx.x, wave = tid >> 6, lane = tid & 63;
    int m0 = blockIdx.y * 128, n0 = blockIdx.x * 128;
    int wm = (wave >> 1) * 64, wn = (wave & 1) * 64;
    int col0 = lane & 15, quad = lane >> 4;

    f32x4 acc[4][4] = {};

    for (int kt = 0; kt < 16; ++kt) {
        int k0 = kt * 64;
        __syncthreads();
#pragma unroll
        for (int it = 0; it < 4; ++it) {
            int gci = (wave * 4 + it) * 64 + lane;
            int r = gci >> 3, c = gci & 7;
            int sc = c ^ (r & 7);
            const ushortT* ga = A + (size_t)(m0 + r) * K + k0 + sc * 8;
            __builtin_amdgcn_global_load_lds(
                (const __attribute__((address_space(1))) unsigned int*)ga,
                (__attribute__((address_space(3))) unsigned int*)(As + (wave * 4 + it) * 512),
                16, 0, 0);
            const ushortT* gb = Bt + (size_t)(n0 + r) * K + k0 + sc * 8;
            __builtin_amdgcn_global_load_lds(
                (const __attribute__((address_space(1))) unsigned int*)gb,
                (__attribute__((address_space(3))) unsigned int*)(Bs + (wave * 4 + it) * 512),
                16, 0, 0);
        }
        __syncthreads();
#pragma unroll
        for (int s = 0; s < 2; ++s) {
            int g = s * 4 + quad;
            bf16x8 af[4], bfr[4];
#pragma unroll
            for (int mi = 0; mi < 4; ++mi) {
                int r = wm + mi * 16 + col0;
                af[mi] = *(const bf16x8*)(As + r * 64 + ((g ^ (r & 7)) * 8));
            }
#pragma unroll
            for (int ni = 0; ni < 4; ++ni) {
                int r = wn + ni * 16 + col0;
                bfr[ni] = *(const bf16x8*)(Bs + r * 64 + ((g ^ (r & 7)) * 8));
            }
#pragma unroll
            for (int mi = 0; mi < 4; ++mi)
#pragma unroll
                for (int ni = 0; ni < 4; ++ni)
                    acc[mi][ni] = __builtin_amdgcn_mfma_f32_16x16x32_bf16(
                        af[mi], bfr[ni], acc[mi][ni], 0, 0, 0);
        }
    }
    __syncthreads();

    int sec = n0 >> 10, cb = n0 & 1023;
    int b = m0 >> 10, tbase = m0 & 1023;

    if (sec < 2) {
        float2* tab = (float2*)smem;   // [tl][p], stride 33
#pragma unroll
        for (int i = 0; i < 16; ++i) {
            int task = i * 256 + tid;
            int tl = task >> 5, p = task & 31;
            float theta = __expf(-(float)p * 0.28782313662425572f);
            float ang = (float)(tbase + tl) * theta;
            float sn, cs;
            sincosf(ang, &sn, &cs);
            tab[tl * 33 + p] = make_float2(cs, sn);
        }
        __syncthreads();
        ushortT* Out = sec ? Kb : Qb;
        float qs = sec ? 1.0f : QSCALE;
#pragma unroll
        for (int mi = 0; mi < 4; ++mi) {
#pragma unroll
            for (int j = 0; j < 4; ++j) {
                int tl = wm + mi * 16 + quad * 4 + j;
                int t = tbase + tl;
                bool valid = t < T_;
#pragma unroll
                for (int nt = 0; nt < 4; ++nt) {
                    float xv = acc[mi][nt][j];
                    float xp = __shfl_xor(xv, 1);
                    int cl = wn + nt * 16 + col0;
                    int d = cl & 63;
                    float2 cssn = tab[tl * 33 + (d >> 1)];
                    float r = (d & 1) ? (xv * cssn.x + xp * cssn.y)
                                      : (xv * cssn.x - xp * cssn.y);
                    r *= qs;
                    if (valid)
                        Out[((size_t)((b << 4) | ((cb + cl) >> 6)) << 16) + (t << 6) + d] = f2bf(r);
                }
            }
        }
    } else {
        ushortT* Ls = smem;   // [col 128][stride 132]
#pragma unroll
        for (int mi = 0; mi < 4; ++mi) {
#pragma unroll
            for (int nt = 0; nt < 4; ++nt) {
                int cl = wn + nt * 16 + col0;
                int rb = wm + mi * 16 + quad * 4;
                uintT lo = (uintT)f2bf(acc[mi][nt][0]) | ((uintT)f2bf(acc[mi][nt][1]) << 16);
                uintT hi = (uintT)f2bf(acc[mi][nt][2]) | ((uintT)f2bf(acc[mi][nt][3]) << 16);
                *(uint2*)(Ls + cl * 132 + rb) = make_uint2(lo, hi);
            }
        }
        __syncthreads();
#pragma unroll
        for (int it = 0; it < 8; ++it) {
            int u = it * 256 + tid;
            int cl = u >> 4, c = u & 15;
            int d = cl & 63, h = (cb + cl) >> 6;
            ushortT tmp[8];
#pragma unroll
            for (int j = 0; j < 8; ++j) tmp[j] = Ls[cl * 132 + j * 16 + c];
            *(bf16x8*)(Vtb + (((size_t)((b << 4) | h)) << 16) + ((size_t)d << 10) + tbase + c * 8)
                = *(bf16x8*)tmp;
        }
    }
}

// ================ MFMA flash attention, 64-q tiles (R4 structure), XCD-aware swizzle
#define PSTR 136
template <bool LAST>
__device__ __forceinline__ void softmax_store(f32x4* sc4, ushortT* Ps,
                                              int wave, int quad, int col0,
                                              int q0, int j0) {
#pragma unroll
    for (int reg = 0; reg < 4; ++reg) {
        int m = quad * 4 + reg;
        int q = q0 + wave * 16 + m;
        float pv[8];
#pragma unroll
        for (int nt = 0; nt < 8; ++nt) {
            float p = fast_exp2(sc4[nt][reg]);
            if (LAST && (j0 + nt * 16 + col0) > q) p = 0.f;
            pv[nt] = p;
        }
        int4 pk;
        pk.x = __builtin_amdgcn_perm(__float_as_uint(pv[1]), __float_as_uint(pv[0]), 0x07060302u);
        pk.y = __builtin_amdgcn_perm(__float_as_uint(pv[3]), __float_as_uint(pv[2]), 0x07060302u);
        pk.z = __builtin_amdgcn_perm(__float_as_uint(pv[5]), __float_as_uint(pv[4]), 0x07060302u);
        pk.w = __builtin_amdgcn_perm(__float_as_uint(pv[7]), __float_as_uint(pv[6]), 0x07060302u);
        *(int4*)(Ps + (wave * 16 + m) * PSTR + col0 * 8) = pk;
    }
}

__global__ __launch_bounds__(256, 3) void attn_mfma_kernel(
    const ushortT* __restrict__ Qb, const ushortT* __restrict__ Kb,
    const ushortT* __restrict__ Vtb, ushortT* __restrict__ Yb)
{
    __shared__ __align__(16) ushortT Ks[128 * 64];    // 16 KB
    __shared__ __align__(16) ushortT Vs[64 * 128];    // 16 KB
    __shared__ __align__(16) ushortT Ps[64 * PSTR];   // 17 KB

    // XCD-aware swizzle: dispatch heuristic xcd = flat % 8. XCD k gets only
    // bh in [8k, 8k+8) (K/V footprint 2 MB < 4 MB per-XCD L2), heavy qi first.
    int flat = blockIdx.y * 64 + blockIdx.x;    // 0..1023 in dispatch order
    int xcd = flat & 7;
    int slot = flat >> 3;                       // 0..127 per XCD
    int bh = xcd * 8 + (slot & 7);
    int qi = 15 - (slot >> 3);                  // heavy blocks first
    int b = bh >> 4, h = bh & 15;
    int q0 = qi * 64;
    int tid = threadIdx.x, wave = tid >> 6, lane = tid & 63;
    int col0 = lane & 15, quad = lane >> 4;

    const ushortT* Kbh  = Kb  + ((size_t)bh << 16);
    const ushortT* Vtbh = Vtb + ((size_t)bh << 16);

    const ushortT* qrowp = Qb + ((size_t)bh << 16) + (size_t)(q0 + wave * 16 + col0) * 64;
    bf16x8 aq[2];
    aq[0] = *(const bf16x8*)(qrowp + quad * 8);
    aq[1] = *(const bf16x8*)(qrowp + 32 + quad * 8);

    bf16x8 onesb;
#pragma unroll
    for (int i = 0; i < 8; ++i) onesb[i] = (short)0x3F80;

    f32x4 o[4] = {};
    f32x4 lsum = {};

    int nchunks = qi / 2 + 1;
    for (int cc = 0; cc < nchunks; ++cc) {
        int j0 = cc * 128;
        __syncthreads();
#pragma unroll
        for (int it = 0; it < 4; ++it) {
            int gci = (wave * 4 + it) * 64 + lane;
            {
                int r = gci >> 3, c = gci & 7;
                int sc = c ^ (r & 7);
                const ushortT* gk = Kbh + (size_t)(j0 + r) * 64 + sc * 8;
                __builtin_amdgcn_global_load_lds(
                    (const __attribute__((address_space(1))) unsigned int*)gk,
                    (__attribute__((address_space(3))) unsigned int*)(Ks + (wave * 4 + it) * 512),
                    16, 0, 0);
            }
            {
                int d = gci >> 4, c = gci & 15;
                int sc = c ^ (d & 15);
                const ushortT* gv = Vtbh + (size_t)d * 1024 + j0 + sc * 8;
                __builtin_amdgcn_global_load_lds(
                    (const __attribute__((address_space(1))) unsigned int*)gv,
                    (__attribute__((address_space(3))) unsigned int*)(Vs + (wave * 4 + it) * 512),
                    16, 0, 0);
            }
        }
        __syncthreads();

        f32x4 sc4[8] = {};
#pragma unroll
        for (int s = 0; s < 2; ++s) {
#pragma unroll
            for (int nt = 0; nt < 8; ++nt) {
                int r = nt * 16 + col0;
                bf16x8 bk = *(const bf16x8*)(Ks + r * 64 + (((s * 4 + quad) ^ (col0 & 7)) * 8));
                sc4[nt] = __builtin_amdgcn_mfma_f32_16x16x32_bf16(aq[s], bk, sc4[nt], 0, 0, 0);
            }
        }

        if (cc == nchunks - 1)
            softmax_store<true>(sc4, Ps, wave, quad, col0, q0, j0);
        else
            softmax_store<false>(sc4, Ps, wave, quad, col0, q0, j0);

#pragma unroll
        for (int s = 0; s < 4; ++s) {
            bf16x8 ap = *(const bf16x8*)(Ps + (wave * 16 + col0) * PSTR + s * 32 + quad * 8);
            lsum = __builtin_amdgcn_mfma_f32_16x16x32_bf16(ap, onesb, lsum, 0, 0, 0);
#pragma unroll
            for (int nt = 0; nt < 4; ++nt) {
                int d = nt * 16 + col0;
                bf16x8 bv = *(const bf16x8*)(Vs + d * 128 + (((s * 4 + quad) ^ col0) * 8));
                o[nt] = __builtin_amdgcn_mfma_f32_16x16x32_bf16(ap, bv, o[nt], 0, 0, 0);
            }
        }
    }

#pragma unroll
    for (int reg = 0; reg < 4; ++reg) {
        int q = q0 + wave * 16 + quad * 4 + reg;
        if (q < T_) {
            float inv_l = 1.0f / lsum[reg];
            ushortT* yp = Yb + ((size_t)(b * 1024 + q) << 10) + h * 64;
#pragma unroll
            for (int nt = 0; nt < 4; ++nt)
                yp[nt * 16 + col0] = f2bf(o[nt][reg] * inv_l);
        }
    }
}

// ================ Proj GEMM: 64x128 tile, row-remap fp32 store
__global__ __launch_bounds__(256, 3) void gemm_proj_kernel(
    const ushortT* __restrict__ A, const ushortT* __restrict__ Bt,
    float* __restrict__ Cout)
{
    __shared__ __align__(16) ushortT As[64 * 64];
    __shared__ __align__(16) ushortT Bs[128 * 64];
    const int K = 1024;
    int tid = threadIdx.x, wave = tid >> 6, lane = tid & 63;
    int m0 = blockIdx.y * 64, n0 = blockIdx.x * 128;
    int wm = (wave >> 1) * 32, wn = (wave & 1) * 64;
    int col0 = lane & 15, quad = lane >> 4;

    f32x4 acc[2][4] = {};

    for (int kt = 0; kt < 16; ++kt) {
        int k0 = kt * 64;
        __syncthreads();
#pragma unroll
        for (int it = 0; it < 2; ++it) {
            int gci = it * 256 + tid;
            int r = gci >> 3, c = gci & 7;
            int sc = c ^ (r & 7);
            const ushortT* ga = A + (size_t)(m0 + r) * K + k0 + sc * 8;
            __builtin_amdgcn_global_load_lds(
                (const __attribute__((address_space(1))) unsigned int*)ga,
                (__attribute__((address_space(3))) unsigned int*)(As + it * 2048 + wave * 512),
                16, 0, 0);
        }
#pragma unroll
        for (int it = 0; it < 4; ++it) {
            int gci = it * 256 + tid;
            int r = gci >> 3, c = gci & 7;
            int sc = c ^ (r & 7);
            const ushortT* gb = Bt + (size_t)(n0 + r) * K + k0 + sc * 8;
            __builtin_amdgcn_global_load_lds(
                (const __attribute__((address_space(1))) unsigned int*)gb,
                (__attribute__((address_space(3))) unsigned int*)(Bs + it * 2048 + wave * 512),
                16, 0, 0);
        }
        __syncthreads();
#pragma unroll
        for (int s = 0; s < 2; ++s) {
            int g = s * 4 + quad;
            bf16x8 af[2], bfr[4];
#pragma unroll
            for (int mi = 0; mi < 2; ++mi) {
                int r = wm + mi * 16 + col0;
                af[mi] = *(const bf16x8*)(As + r * 64 + ((g ^ (r & 7)) * 8));
            }
#pragma unroll
            for (int ni = 0; ni < 4; ++ni) {
                int r = wn + ni * 16 + col0;
                bfr[ni] = *(const bf16x8*)(Bs + r * 64 + ((g ^ (r & 7)) * 8));
            }
#pragma unroll
            for (int mi = 0; mi < 2; ++mi)
#pragma unroll
                for (int ni = 0; ni < 4; ++ni)
                    acc[mi][ni] = __builtin_amdgcn_mfma_f32_16x16x32_bf16(
                        af[mi], bfr[ni], acc[mi][ni], 0, 0, 0);
        }
    }

#pragma unroll
    for (int mi = 0; mi < 2; ++mi) {
#pragma unroll
        for (int j = 0; j < 4; ++j) {
            int row = m0 + wm + mi * 16 + quad * 4 + j;
            int t = row & 1023, b = row >> 10;
            if (t < T_) {
                float* cp = Cout + ((size_t)(b * T_ + t) << 10) + n0 + wn;
#pragma unroll
                for (int ni = 0; ni < 4; ++ni)
                    cp[ni * 16 + col0] = acc[mi][ni][j];
            }
        }
    }
}

extern "C" void kernel_launch(void* const* d_in, const int* in_sizes, int n_in,
                              void* d_out, int out_size, void* d_ws, size_t ws_size,
                              hipStream_t stream) {
    const float* x      = (const float*)d_in[0];
    const float* W_attn = (const float*)d_in[2];
    const float* W_proj = (const float*)d_in[3];
    float* out = (float*)d_out;

    uintptr_t w = (uintptr_t)d_ws;
    ushortT* Xb  = (ushortT*)(w);                   //  8 MB  bf16 [4096][1024] (padded rows)
    ushortT* Wat = (ushortT*)(w + 8388608);         //  6 MB  bf16 [3072][1024]
    ushortT* Wpt = (ushortT*)(w + 14680064);        //  2 MB  bf16 [1024][1024]
    ushortT* Qb  = (ushortT*)(w + 16777216);        //  8 MB  bf16 [64bh][1024][64]
    ushortT* Kb  = (ushortT*)(w + 25165824);        //  8 MB
    ushortT* Vtb = (ushortT*)(w + 33554432);        //  8 MB  bf16 [64bh][64][1024] (pi-permuted)
    ushortT* Yb  = (ushortT*)(w + 41943040);        //  8 MB  bf16 [4096][1024] (padded rows)

    prep_kernel<<<dim3(5120), dim3(256), 0, stream>>>(x, W_attn, W_proj, Xb, Wat, Wpt);

    gemm_qkv_kernel<<<dim3(24, 32), dim3(256), 0, stream>>>(Xb, Wat, Qb, Kb, Vtb);

    attn_mfma_kernel<<<dim3(64, 16), dim3(256), 0, stream>>>(Qb, Kb, Vtb, Yb);

    gemm_proj_kernel<<<dim3(8, 64), dim3(256), 0, stream>>>(Yb, Wpt, out);
}